// Round 16
// baseline (520.267 us; speedup 1.0000x reference)
//
#include <hip/hip_runtime.h>
#include <hip/hip_bf16.h>
#include <math.h>

#define NATOMS 1024          // B*A
#define NGRID  6912          // B*NG
#define NNODES 7936
#define NG_PER 1728
#define KA 8
#define KG 32
#define CODE 64
#define HID 128

typedef __hip_bfloat16 bf16;
typedef unsigned long long u64;
typedef unsigned int u32;

// Fallback workspace allocated at library load (legal: outside kernel_launch).
static void* g_buf = nullptr;
__attribute__((constructor)) static void _alloc_ws(){
  if (hipMalloc(&g_buf, (size_t)24 * 1024 * 1024) != hipSuccess) g_buf = nullptr;
}

// dtype-agnostic float load: element i of buffer p, fp32 if f32!=0 else bf16
__device__ __forceinline__ float ldf(const void* p, size_t i, int f32){
  return f32 ? ((const float*)p)[i] : __bfloat162float(((const bf16*)p)[i]);
}

// dtype-agnostic int load: mode 0=int32, 1=int64(LE), 2=f32, 3=bf16
__device__ __forceinline__ int ldt(const void* p, int i, int mode){
  switch(mode){
    case 1:  return ((const int*)p)[2*i];
    case 2:  return (int)((const float*)p)[i];
    case 3:  return (int)__bfloat162float(((const bf16*)p)[i]);
    default: return ((const int*)p)[i];
  }
}

// ---------- block 0: pos dtype detect; block 1: types dtype + gauss consts ----------
__global__ void k0(const unsigned short* __restrict__ posu,
                   const unsigned short* __restrict__ typu,
                   int* __restrict__ flag, float* __restrict__ offc){
  if (blockIdx.x == 0){
    __shared__ int scnt;
    int t = threadIdx.x;               // 256 threads
    if (t == 0) scnt = 0;
    __syncthreads();
    int c = 0;
    for (int q = 0; q < 12; q++){
      unsigned short u = posu[t + 256*q];
      int e = (u >> 7) & 0xFF;
      if (e >= 140) c++;
    }
    atomicAdd(&scnt, c);
    __syncthreads();
    if (t == 0) flag[0] = (scnt > 16) ? 1 : 0;
  } else {
    if (threadIdx.x == 0){
      int oddHigh = 0, evenHigh = 0, quadZero = 1;
      for (int k = 0; k < 16; k++){
        unsigned short o = typu[2*k+1], e = typu[2*k];
        if (o >= 0x3F00 && o <= 0x4200) oddHigh++;
        if (e >= 0x3F00 && e <= 0x4200) evenHigh++;
      }
      for (int k = 0; k < 16; k++) if (typu[4*k+2] != 0) quadZero = 0;
      int mode;
      if (oddHigh >= 8) mode = (evenHigh >= 8) ? 3 : 2;   // bf16 : f32
      else              mode = quadZero ? 1 : 0;          // int64 : int32
      flag[1] = mode;
    }
    int k = (int)threadIdx.x - 64;
    if (k >= 0 && k < 20){
      double step = log(6.0) / 19.0;
      double offk = exp((double)k * step) - 1.0;
      int km = (k == 0) ? 1 : k;
      double d = (exp((double)km * step) - 1.0) - (exp((double)(km - 1) * step) - 1.0);
      offc[k]      = (float)offk;
      offc[20 + k] = (float)(-0.5 / (d * d));
    }
  }
}

// ---------- merged preamble (r13 version — 1 node/wave kNN, known 42 us):
//   blocks 0..1983 init; 1984..2239 atom kNN; 2240..3967 grid kNN (f64). ----------
__global__ void __launch_bounds__(256) k_pre(const void* __restrict__ pos,
    const void* __restrict__ types, const int* __restrict__ flag,
    float* __restrict__ node_pos, float* __restrict__ h0,
    int* __restrict__ nbrA, int* __restrict__ nbrG){
  #pragma clang fp contract(off)
  int f32 = flag[0];
  int b = blockIdx.x;
  int t = threadIdx.x;
  if (b < 1984){
    // ---- init: node_pos (f32) + h0 one-hot ----
    int tm = flag[1];
    int idx = b * 256 + t;             // < NNODES*64
    if (idx < NNODES){
      if (idx < NATOMS){
        node_pos[idx*3+0] = ldf(pos, idx*3+0, f32);
        node_pos[idx*3+1] = ldf(pos, idx*3+1, f32);
        node_pos[idx*3+2] = ldf(pos, idx*3+2, f32);
      } else {
        int cell = (idx - NATOMS) % NG_PER;
        int ix = cell / 144, iy = (cell / 12) % 12, iz = cell % 12;
        node_pos[idx*3+0] = -8.25f + 1.5f * ix;
        node_pos[idx*3+1] = -8.25f + 1.5f * iy;
        node_pos[idx*3+2] = -8.25f + 1.5f * iz;
      }
    }
    int node = idx >> 6, c = idx & 63;
    float v = 0.f;
    if (node < NATOMS && c == ldt(types, node, tm)) v = 1.f;
    h0[idx] = v;
  } else if (b < 1984 + 256){
    // ---- atom-atom kNN (K=8): u64 key = (f32 d2 bits << 8) | idx (exact lex) ----
    int i = (b - 1984) * 4 + (t >> 6);
    int bb = i >> 8, li = i & 255;
    int l = t & 63;
    float px = ldf(pos,3*i,f32), py = ldf(pos,3*i+1,f32), pz = ldf(pos,3*i+2,f32);
    u64 vals[4];
    for (int q = 0; q < 4; q++){
      int c = l + 64*q;
      int j = (bb << 8) + c;
      float dx = ldf(pos,3*j+0,f32) - px;
      float dy = ldf(pos,3*j+1,f32) - py;
      float dz = ldf(pos,3*j+2,f32) - pz;
      float d2 = (dx*dx + dy*dy) + dz*dz;
      vals[q] = (c == li) ? ~0ull : (((u64)__float_as_uint(d2) << 8) | (unsigned)c);
    }
    for (int it = 0; it < KA; it++){
      u64 v = vals[0];
      for (int q = 1; q < 4; q++) if (vals[q] < v) v = vals[q];
      for (int m = 1; m < 64; m <<= 1){
        u64 ov = __shfl_xor(v, m);
        if (ov < v) v = ov;
      }
      int widx = (int)(v & 0xFF);
      if (l == 0) nbrA[i*KA + it] = (bb << 8) + widx;
      if ((widx & 63) == l) vals[widx >> 6] = ~0ull;
    }
  } else {
    // ---- grid->atom kNN (K=32), f64; key = (f64 bits & ~0xFF) | idx.
    //      2^-44 key precision required (r12: f32 set-substitution failed).
    //      1 node/wave (r15's 4-node interleave regressed 3x: bpermute
    //      throughput-bound, not latency-bound). ----
    int gi = (b - 2240) * 4 + (t >> 6);
    int bb = gi / NG_PER, cell = gi % NG_PER;
    int ix = cell / 144, iy = (cell / 12) % 12, iz = cell % 12;
    double px = -8.25 + 1.5 * ix;
    double py = -8.25 + 1.5 * iy;
    double pz = -8.25 + 1.5 * iz;
    int l = t & 63;
    u64 vals[4];
    for (int q = 0; q < 4; q++){
      int c = l + 64*q;
      int j = (bb << 8) + c;
      double dx = px - (double)ldf(pos,3*j+0,f32);
      double dy = py - (double)ldf(pos,3*j+1,f32);
      double dz = pz - (double)ldf(pos,3*j+2,f32);
      double d2 = dx*dx + dy*dy + dz*dz;
      vals[q] = ((u64)__double_as_longlong(d2) & ~0xFFull) | (unsigned)c;
    }
    for (int it = 0; it < KG; it++){
      u64 v = vals[0];
      for (int q = 1; q < 4; q++) if (vals[q] < v) v = vals[q];
      for (int m = 1; m < 64; m <<= 1){
        u64 ov = __shfl_xor(v, m);
        if (ov < v) v = ov;
      }
      int widx = (int)(v & 0xFF);
      if (l == 0) nbrG[gi*KG + it] = (bb << 8) + widx;
      if ((widx & 63) == l) vals[widx >> 6] = ~0ull;
    }
  }
}

// ---------- fused per-layer folds, W column in registers:
//   blocks 0..991:   Xd rows (8/block) = h @ W1dst
//   blocks 992..1119: Xs rows (8/block) = h @ W1src (atoms)
//   block 1120:      Wg = eW @ W1c, b1p = b1 + eb @ W1c ----------
__global__ void __launch_bounds__(128) k_fold(const float* __restrict__ hin,
    const void* __restrict__ W1, const void* __restrict__ b1,
    const void* __restrict__ eW, const void* __restrict__ eb,
    size_t wl, size_t b1o, size_t eWo, size_t ebo,
    const int* __restrict__ flag,
    float* __restrict__ Xd, float* __restrict__ Xs,
    float* __restrict__ Wg, float* __restrict__ b1p)
{
  __shared__ __attribute__((aligned(16))) float sA[1344];
  int f32 = flag[0];
  int t = threadIdx.x;
  int b = blockIdx.x;
  if (b < 1120){
    int isXd = (b < 992);
    size_t wo = wl + (isXd ? (size_t)64*128 : 0);
    int r0 = (isXd ? b : (b - 992)) * 8;
    float* C = isXd ? Xd : Xs;
    float w[64];
    #pragma unroll
    for (int k = 0; k < 64; k++) w[k] = ldf(W1, wo + (size_t)k*128 + t, f32);
    for (int i = t; i < 8*64; i += 128) sA[i] = hin[(size_t)r0*64 + i];
    __syncthreads();
    #pragma unroll
    for (int r = 0; r < 8; r += 4){
      float a0 = 0.f, a1 = 0.f, a2 = 0.f, a3 = 0.f;
      #pragma unroll
      for (int k4 = 0; k4 < 16; k4++){
        float4 v0 = *(const float4*)&sA[(r+0)*64 + 4*k4];
        float4 v1 = *(const float4*)&sA[(r+1)*64 + 4*k4];
        float4 v2 = *(const float4*)&sA[(r+2)*64 + 4*k4];
        float4 v3 = *(const float4*)&sA[(r+3)*64 + 4*k4];
        a0 = fmaf(v0.x, w[4*k4+0], a0); a0 = fmaf(v0.y, w[4*k4+1], a0);
        a0 = fmaf(v0.z, w[4*k4+2], a0); a0 = fmaf(v0.w, w[4*k4+3], a0);
        a1 = fmaf(v1.x, w[4*k4+0], a1); a1 = fmaf(v1.y, w[4*k4+1], a1);
        a1 = fmaf(v1.z, w[4*k4+2], a1); a1 = fmaf(v1.w, w[4*k4+3], a1);
        a2 = fmaf(v2.x, w[4*k4+0], a2); a2 = fmaf(v2.y, w[4*k4+1], a2);
        a2 = fmaf(v2.z, w[4*k4+2], a2); a2 = fmaf(v2.w, w[4*k4+3], a2);
        a3 = fmaf(v3.x, w[4*k4+0], a3); a3 = fmaf(v3.y, w[4*k4+1], a3);
        a3 = fmaf(v3.z, w[4*k4+2], a3); a3 = fmaf(v3.w, w[4*k4+3], a3);
      }
      C[(size_t)(r0 + r + 0)*128 + t] = a0;
      C[(size_t)(r0 + r + 1)*128 + t] = a1;
      C[(size_t)(r0 + r + 2)*128 + t] = a2;
      C[(size_t)(r0 + r + 3)*128 + t] = a3;
    }
  } else {
    // Wg fold: w = W1c column t in regs; eW/eb staged in LDS
    float w[64];
    #pragma unroll
    for (int k = 0; k < 64; k++) w[k] = ldf(W1, wl + (size_t)128*128 + (size_t)k*128 + t, f32);
    for (int i = t; i < 20*64; i += 128) sA[i] = ldf(eW, eWo + i, f32);
    if (t < 64) sA[1280 + t] = ldf(eb, ebo + t, f32);
    __syncthreads();
    for (int g = 0; g < 20; g++){
      float acc = 0.f;
      #pragma unroll
      for (int k4 = 0; k4 < 16; k4++){
        float4 e = *(const float4*)&sA[g*64 + 4*k4];
        acc = fmaf(e.x, w[4*k4+0], acc); acc = fmaf(e.y, w[4*k4+1], acc);
        acc = fmaf(e.z, w[4*k4+2], acc); acc = fmaf(e.w, w[4*k4+3], acc);
      }
      Wg[g*128 + t] = acc;
    }
    float acc = ldf(b1, b1o + t, f32);
    #pragma unroll
    for (int k4 = 0; k4 < 16; k4++){
      float4 e = *(const float4*)&sA[1280 + 4*k4];
      acc = fmaf(e.x, w[4*k4+0], acc); acc = fmaf(e.y, w[4*k4+1], acc);
      acc = fmaf(e.z, w[4*k4+2], acc); acc = fmaf(e.w, w[4*k4+3], acc);
    }
    b1p[t] = acc;
  }
}

// ---------- fused aggregation + W2 + residual + LayerNorm (one layer step):
//   blocks 0..31: 32 atoms (K=8); 32..895: 8 grid nodes (K=32); 256 threads.
//   Phase 1 (= old k_aggr): S[node][tt] -> LDS sS.
//   Phase 2 (= old k_out): reuse gauss scratch for W2, GEMM + LN in-block. ----------
__global__ void __launch_bounds__(256) k_layer(const float* __restrict__ Xs,
    const float* __restrict__ Xd, const int* __restrict__ nbrA,
    const int* __restrict__ nbrG, const float* __restrict__ node_pos,
    const float* __restrict__ offc, const float* __restrict__ Wg,
    const float* __restrict__ b1p, const float* __restrict__ hin,
    const void* __restrict__ W2, const void* __restrict__ b2,
    const void* __restrict__ lng, const void* __restrict__ lnb,
    size_t w2o, size_t b2o, size_t lno, const int* __restrict__ flag,
    float* __restrict__ hout, float* __restrict__ out, int writeOut)
{
  __shared__ __attribute__((aligned(16))) float smem[8192]; // 32 KB: gauss[256*24] then W2[128*64]
  __shared__ __attribute__((aligned(16))) float sS[32*128]; // 16 KB
  __shared__ int   sN[256];
  __shared__ float sOff[40];
  int f32 = flag[0];
  int t = threadIdx.x;            // 256
  int b = blockIdx.x;
  int isAtom = (b < 32);
  int KK, node0; const int* nbr;
  if (isAtom){ KK = 8;  node0 = b*32;              nbr = nbrA + b*256; }
  else       { KK = 32; node0 = NATOMS + (b-32)*8; nbr = nbrG + (size_t)(b-32)*256; }
  if (t < 40) sOff[t] = offc[t];
  sN[t] = nbr[t];
  __syncthreads();
  {
    // one edge per thread: distance + 20 gaussians
    int node = node0 + (isAtom ? (t >> 3) : (t >> 5));
    int src = sN[t];
    float dx = node_pos[src*3+0] - node_pos[node*3+0];
    float dy = node_pos[src*3+1] - node_pos[node*3+1];
    float dz = node_pos[src*3+2] - node_pos[node*3+2];
    float dist = fminf(sqrtf(dx*dx + dy*dy + dz*dz), 5.0f);
    #pragma unroll
    for (int k = 0; k < 20; k++){
      float dd = dist - sOff[k];
      smem[t*24 + k] = expf(sOff[20+k] * dd * dd);
    }
  }
  int g = t >> 7, tt = t & 127;
  float w[20];
  #pragma unroll
  for (int k = 0; k < 20; k++) w[k] = Wg[k*128 + tt];   // column-constant -> regs
  float b1v = b1p[tt];
  __syncthreads();
  float rK = 1.f / KK;
  int nLoc = isAtom ? 16 : 4;
  int nbase = g * nLoc;
  for (int n = 0; n < nLoc; n++){
    int node = node0 + nbase + n;
    float zb = Xd[(size_t)node*128 + tt] + b1v;
    float S = 0.f;
    int ebase = (nbase + n) * KK;
    for (int e = 0; e < KK; e += 4){
      int i0 = ebase + e;
      int s0 = sN[i0], s1 = sN[i0+1], s2 = sN[i0+2], s3 = sN[i0+3];
      float a0 = zb + Xs[(size_t)s0*128 + tt];
      float a1 = zb + Xs[(size_t)s1*128 + tt];
      float a2 = zb + Xs[(size_t)s2*128 + tt];
      float a3 = zb + Xs[(size_t)s3*128 + tt];
      const float* g0 = &smem[i0*24];
      #pragma unroll
      for (int kq = 0; kq < 5; kq++){
        float4 ga = *(const float4*)(g0 + 4*kq);
        float4 gb = *(const float4*)(g0 + 24 + 4*kq);
        float4 gc = *(const float4*)(g0 + 48 + 4*kq);
        float4 gd = *(const float4*)(g0 + 72 + 4*kq);
        a0 = fmaf(ga.x, w[4*kq+0], a0); a0 = fmaf(ga.y, w[4*kq+1], a0);
        a0 = fmaf(ga.z, w[4*kq+2], a0); a0 = fmaf(ga.w, w[4*kq+3], a0);
        a1 = fmaf(gb.x, w[4*kq+0], a1); a1 = fmaf(gb.y, w[4*kq+1], a1);
        a1 = fmaf(gb.z, w[4*kq+2], a1); a1 = fmaf(gb.w, w[4*kq+3], a1);
        a2 = fmaf(gc.x, w[4*kq+0], a2); a2 = fmaf(gc.y, w[4*kq+1], a2);
        a2 = fmaf(gc.z, w[4*kq+2], a2); a2 = fmaf(gc.w, w[4*kq+3], a2);
        a3 = fmaf(gd.x, w[4*kq+0], a3); a3 = fmaf(gd.y, w[4*kq+1], a3);
        a3 = fmaf(gd.z, w[4*kq+2], a3); a3 = fmaf(gd.w, w[4*kq+3], a3);
      }
      S += fmaxf(a0,0.f) + fmaxf(a1,0.f) + fmaxf(a2,0.f) + fmaxf(a3,0.f);
    }
    sS[(nbase + n)*128 + tt] = S * rK;
  }
  __syncthreads();
  // ---- phase 2: stage W2 over the gauss scratch, then GEMM + residual + LN ----
  for (int i = t; i < 128*64; i += 256) smem[i] = ldf(W2, w2o + i, f32);
  int wv = t >> 6, c = t & 63;
  float b2v = ldf(b2, b2o + c, f32);
  float gv  = ldf(lng, lno + c, f32);
  float bv  = ldf(lnb, lno + c, f32);
  __syncthreads();
  int rpw = isAtom ? 8 : 2;       // rows per wave
  for (int rr = wv*rpw; rr < wv*rpw + rpw; rr += 2){
    float a0 = 0.f, a1 = 0.f;
    const float* s0 = &sS[rr*128];
    const float* s1 = &sS[(rr+1)*128];
    #pragma unroll
    for (int kq = 0; kq < 32; kq++){
      float4 sv0 = *(const float4*)(s0 + 4*kq);
      float4 sv1 = *(const float4*)(s1 + 4*kq);
      a0 = fmaf(sv0.x, smem[(4*kq+0)*64+c], a0);
      a0 = fmaf(sv0.y, smem[(4*kq+1)*64+c], a0);
      a0 = fmaf(sv0.z, smem[(4*kq+2)*64+c], a0);
      a0 = fmaf(sv0.w, smem[(4*kq+3)*64+c], a0);
      a1 = fmaf(sv1.x, smem[(4*kq+0)*64+c], a1);
      a1 = fmaf(sv1.y, smem[(4*kq+1)*64+c], a1);
      a1 = fmaf(sv1.z, smem[(4*kq+2)*64+c], a1);
      a1 = fmaf(sv1.w, smem[(4*kq+3)*64+c], a1);
    }
    {
      int node = node0 + rr;
      float x = hin[(size_t)node*64 + c] + a0 + b2v;
      float s = x;
      #pragma unroll
      for (int m = 1; m < 64; m <<= 1) s += __shfl_xor(s, m);
      float mu = s * (1.f/64.f);
      float d = x - mu;
      float v = d * d;
      #pragma unroll
      for (int m = 1; m < 64; m <<= 1) v += __shfl_xor(v, m);
      v *= (1.f/64.f);
      float o = d / sqrtf(v + 1e-5f) * gv + bv;
      hout[(size_t)node*64 + c] = o;
      if (writeOut && node >= NATOMS) out[(size_t)(node - NATOMS)*64 + c] = o;
    }
    {
      int node = node0 + rr + 1;
      float x = hin[(size_t)node*64 + c] + a1 + b2v;
      float s = x;
      #pragma unroll
      for (int m = 1; m < 64; m <<= 1) s += __shfl_xor(s, m);
      float mu = s * (1.f/64.f);
      float d = x - mu;
      float v = d * d;
      #pragma unroll
      for (int m = 1; m < 64; m <<= 1) v += __shfl_xor(v, m);
      v *= (1.f/64.f);
      float o = d / sqrtf(v + 1e-5f) * gv + bv;
      hout[(size_t)node*64 + c] = o;
      if (writeOut && node >= NATOMS) out[(size_t)(node - NATOMS)*64 + c] = o;
    }
  }
}

extern "C" void kernel_launch(void* const* d_in, const int* in_sizes, int n_in,
                              void* d_out, int out_size, void* d_ws, size_t ws_size,
                              hipStream_t stream) {
  const void* pos    = d_in[0];
  const void* types  = d_in[1];
  // d_in[2] = batch (unused by the math)
  const void* edge_W = d_in[3];
  const void* edge_b = d_in[4];
  const void* W1     = d_in[5];
  const void* b1     = d_in[6];
  const void* W2     = d_in[7];
  const void* b2     = d_in[8];
  const void* lng    = d_in[9];
  const void* lnb    = d_in[10];

  const size_t NEED = (size_t)16 * 1024 * 1024;
  char* w = (ws_size >= NEED) ? (char*)d_ws : (char*)g_buf;
  if (w == nullptr) w = (char*)d_ws;   // last resort

  size_t o = 0;
  auto alloc = [&](size_t bytes)->char*{
    char* r = w + o; o = (o + bytes + 255) & ~(size_t)255; return r;
  };
  float*  node_pos = (float*) alloc((size_t)NNODES*3*4);
  float*  hA       = (float*) alloc((size_t)NNODES*CODE*4);
  float*  hB       = (float*) alloc((size_t)NNODES*CODE*4);
  float*  Xs       = (float*) alloc((size_t)NATOMS*HID*4);
  float*  Xd       = (float*) alloc((size_t)NNODES*HID*4);
  int*    nbrA     = (int*)   alloc((size_t)NATOMS*KA*4);
  int*    nbrG     = (int*)   alloc((size_t)NGRID*KG*4);
  float*  offc     = (float*) alloc(64*4);
  float*  Wg       = (float*) alloc(20*HID*4);
  float*  b1p      = (float*) alloc(HID*4);
  int*    flag     = (int*)   alloc(64*4);

  k0<<<2, 256, 0, stream>>>((const unsigned short*)pos,
                            (const unsigned short*)types, flag, offc);
  k_pre<<<3968, 256, 0, stream>>>(pos, types, flag, node_pos, hA, nbrA, nbrG);

  float* hin = hA; float* hout = hB;
  for (int l = 0; l < 4; l++){
    size_t wl  = (size_t)l*192*128;
    size_t eWo = (size_t)l*20*64, ebo = (size_t)l*64;
    size_t b1o = (size_t)l*128,   w2o = (size_t)l*128*64;
    size_t b2o = (size_t)l*64,    lno = (size_t)l*64;
    k_fold<<<1121, 128, 0, stream>>>(hin, W1, b1, edge_W, edge_b,
                                     wl, b1o, eWo, ebo, flag, Xd, Xs, Wg, b1p);
    k_layer<<<32 + NGRID/8, 256, 0, stream>>>(Xs, Xd, nbrA, nbrG, node_pos,
                                              offc, Wg, b1p, hin, W2, b2, lng, lnb,
                                              w2o, b2o, lno, flag,
                                              hout, (float*)d_out, (l == 3) ? 1 : 0);
    float* tmp = hin; hin = hout; hout = tmp;
  }
}

// Round 17
// 389.229 us; speedup vs baseline: 1.3367x; 1.3367x over previous
//
#include <hip/hip_runtime.h>
#include <hip/hip_bf16.h>
#include <math.h>

#define NATOMS 1024          // B*A
#define NGRID  6912          // B*NG
#define NNODES 7936
#define NG_PER 1728
#define KA 8
#define KG 32
#define CODE 64
#define HID 128

typedef __hip_bfloat16 bf16;
typedef unsigned long long u64;
typedef unsigned int u32;

// Fallback workspace allocated at library load (legal: outside kernel_launch).
static void* g_buf = nullptr;
__attribute__((constructor)) static void _alloc_ws(){
  if (hipMalloc(&g_buf, (size_t)24 * 1024 * 1024) != hipSuccess) g_buf = nullptr;
}

// dtype-agnostic float load: element i of buffer p, fp32 if f32!=0 else bf16
__device__ __forceinline__ float ldf(const void* p, size_t i, int f32){
  return f32 ? ((const float*)p)[i] : __bfloat162float(((const bf16*)p)[i]);
}

// dtype-agnostic int load: mode 0=int32, 1=int64(LE), 2=f32, 3=bf16
__device__ __forceinline__ int ldt(const void* p, int i, int mode){
  switch(mode){
    case 1:  return ((const int*)p)[2*i];
    case 2:  return (int)((const float*)p)[i];
    case 3:  return (int)__bfloat162float(((const bf16*)p)[i]);
    default: return ((const int*)p)[i];
  }
}

// ---------- block 0: pos dtype detect; block 1: types dtype + gauss consts ----------
__global__ void k0(const unsigned short* __restrict__ posu,
                   const unsigned short* __restrict__ typu,
                   int* __restrict__ flag, float* __restrict__ offc){
  if (blockIdx.x == 0){
    __shared__ int scnt;
    int t = threadIdx.x;               // 256 threads
    if (t == 0) scnt = 0;
    __syncthreads();
    int c = 0;
    for (int q = 0; q < 12; q++){
      unsigned short u = posu[t + 256*q];
      int e = (u >> 7) & 0xFF;
      if (e >= 140) c++;
    }
    atomicAdd(&scnt, c);
    __syncthreads();
    if (t == 0) flag[0] = (scnt > 16) ? 1 : 0;
  } else {
    if (threadIdx.x == 0){
      int oddHigh = 0, evenHigh = 0, quadZero = 1;
      for (int k = 0; k < 16; k++){
        unsigned short o = typu[2*k+1], e = typu[2*k];
        if (o >= 0x3F00 && o <= 0x4200) oddHigh++;
        if (e >= 0x3F00 && e <= 0x4200) evenHigh++;
      }
      for (int k = 0; k < 16; k++) if (typu[4*k+2] != 0) quadZero = 0;
      int mode;
      if (oddHigh >= 8) mode = (evenHigh >= 8) ? 3 : 2;   // bf16 : f32
      else              mode = quadZero ? 1 : 0;          // int64 : int32
      flag[1] = mode;
    }
    int k = (int)threadIdx.x - 64;
    if (k >= 0 && k < 20){
      double step = log(6.0) / 19.0;
      double offk = exp((double)k * step) - 1.0;
      int km = (k == 0) ? 1 : k;
      double d = (exp((double)km * step) - 1.0) - (exp((double)(km - 1) * step) - 1.0);
      offc[k]      = (float)offk;
      offc[20 + k] = (float)(-0.5 / (d * d));
    }
  }
}

// ---------- merged preamble: blocks 0..1983 init; 1984..2239 atom kNN;
//            2240..3967 grid kNN (f64 — matches checker; f32 regressed r12). ----------
__global__ void __launch_bounds__(256) k_pre(const void* __restrict__ pos,
    const void* __restrict__ types, const int* __restrict__ flag,
    float* __restrict__ node_pos, float* __restrict__ h0,
    int* __restrict__ nbrA, int* __restrict__ nbrG){
  #pragma clang fp contract(off)
  int f32 = flag[0];
  int b = blockIdx.x;
  int t = threadIdx.x;
  if (b < 1984){
    // ---- init: node_pos (f32) + h0 one-hot ----
    int tm = flag[1];
    int idx = b * 256 + t;             // < NNODES*64
    if (idx < NNODES){
      if (idx < NATOMS){
        node_pos[idx*3+0] = ldf(pos, idx*3+0, f32);
        node_pos[idx*3+1] = ldf(pos, idx*3+1, f32);
        node_pos[idx*3+2] = ldf(pos, idx*3+2, f32);
      } else {
        int cell = (idx - NATOMS) % NG_PER;
        int ix = cell / 144, iy = (cell / 12) % 12, iz = cell % 12;
        node_pos[idx*3+0] = -8.25f + 1.5f * ix;
        node_pos[idx*3+1] = -8.25f + 1.5f * iy;
        node_pos[idx*3+2] = -8.25f + 1.5f * iz;
      }
    }
    int node = idx >> 6, c = idx & 63;
    float v = 0.f;
    if (node < NATOMS && c == ldt(types, node, tm)) v = 1.f;
    h0[idx] = v;
  } else if (b < 1984 + 256){
    // ---- atom-atom kNN (K=8): u64 key = (f32 d2 bits << 8) | idx (exact lex) ----
    int i = (b - 1984) * 4 + (t >> 6);
    int bb = i >> 8, li = i & 255;
    int l = t & 63;
    float px = ldf(pos,3*i,f32), py = ldf(pos,3*i+1,f32), pz = ldf(pos,3*i+2,f32);
    u64 vals[4];
    for (int q = 0; q < 4; q++){
      int c = l + 64*q;
      int j = (bb << 8) + c;
      float dx = ldf(pos,3*j+0,f32) - px;
      float dy = ldf(pos,3*j+1,f32) - py;
      float dz = ldf(pos,3*j+2,f32) - pz;
      float d2 = (dx*dx + dy*dy) + dz*dz;
      vals[q] = (c == li) ? ~0ull : (((u64)__float_as_uint(d2) << 8) | (unsigned)c);
    }
    for (int it = 0; it < KA; it++){
      u64 v = vals[0];
      for (int q = 1; q < 4; q++) if (vals[q] < v) v = vals[q];
      for (int m = 1; m < 64; m <<= 1){
        u64 ov = __shfl_xor(v, m);
        if (ov < v) v = ov;
      }
      int widx = (int)(v & 0xFF);
      if (l == 0) nbrA[i*KA + it] = (bb << 8) + widx;
      if ((widx & 63) == l) vals[widx >> 6] = ~0ull;
    }
  } else {
    // ---- grid->atom kNN (K=32), f64; key = (f64 bits & ~0xFF) | idx.
    //      2^-44 key precision required (r12: f32 keys failed at 0.17 absmax).
    //      1 node/wave (r15's 4-node interleave regressed 3x: bpermute is
    //      throughput-bound, not latency-bound). ----
    int gi = (b - 2240) * 4 + (t >> 6);
    int bb = gi / NG_PER, cell = gi % NG_PER;
    int ix = cell / 144, iy = (cell / 12) % 12, iz = cell % 12;
    double px = -8.25 + 1.5 * ix;
    double py = -8.25 + 1.5 * iy;
    double pz = -8.25 + 1.5 * iz;
    int l = t & 63;
    u64 vals[4];
    for (int q = 0; q < 4; q++){
      int c = l + 64*q;
      int j = (bb << 8) + c;
      double dx = px - (double)ldf(pos,3*j+0,f32);
      double dy = py - (double)ldf(pos,3*j+1,f32);
      double dz = pz - (double)ldf(pos,3*j+2,f32);
      double d2 = dx*dx + dy*dy + dz*dz;
      vals[q] = ((u64)__double_as_longlong(d2) & ~0xFFull) | (unsigned)c;
    }
    for (int it = 0; it < KG; it++){
      u64 v = vals[0];
      for (int q = 1; q < 4; q++) if (vals[q] < v) v = vals[q];
      for (int m = 1; m < 64; m <<= 1){
        u64 ov = __shfl_xor(v, m);
        if (ov < v) v = ov;
      }
      int widx = (int)(v & 0xFF);
      if (l == 0) nbrG[gi*KG + it] = (bb << 8) + widx;
      if ((widx & 63) == l) vals[widx >> 6] = ~0ull;
    }
  }
}

// ---------- fused per-layer folds, W column in registers:
//   blocks 0..991:   Xd rows (8/block) = h @ W1dst
//   blocks 992..1119: Xs rows (8/block) = h @ W1src (atoms)
//   block 1120:      Wg = eW @ W1c, b1p = b1 + eb @ W1c ----------
__global__ void __launch_bounds__(128) k_fold(const float* __restrict__ hin,
    const void* __restrict__ W1, const void* __restrict__ b1,
    const void* __restrict__ eW, const void* __restrict__ eb,
    size_t wl, size_t b1o, size_t eWo, size_t ebo,
    const int* __restrict__ flag,
    float* __restrict__ Xd, float* __restrict__ Xs,
    float* __restrict__ Wg, float* __restrict__ b1p)
{
  __shared__ __attribute__((aligned(16))) float sA[1344];
  int f32 = flag[0];
  int t = threadIdx.x;
  int b = blockIdx.x;
  if (b < 1120){
    int isXd = (b < 992);
    size_t wo = wl + (isXd ? (size_t)64*128 : 0);
    int r0 = (isXd ? b : (b - 992)) * 8;
    float* C = isXd ? Xd : Xs;
    float w[64];
    #pragma unroll
    for (int k = 0; k < 64; k++) w[k] = ldf(W1, wo + (size_t)k*128 + t, f32);
    for (int i = t; i < 8*64; i += 128) sA[i] = hin[(size_t)r0*64 + i];
    __syncthreads();
    #pragma unroll
    for (int r = 0; r < 8; r += 4){
      float a0 = 0.f, a1 = 0.f, a2 = 0.f, a3 = 0.f;
      #pragma unroll
      for (int k4 = 0; k4 < 16; k4++){
        float4 v0 = *(const float4*)&sA[(r+0)*64 + 4*k4];
        float4 v1 = *(const float4*)&sA[(r+1)*64 + 4*k4];
        float4 v2 = *(const float4*)&sA[(r+2)*64 + 4*k4];
        float4 v3 = *(const float4*)&sA[(r+3)*64 + 4*k4];
        a0 = fmaf(v0.x, w[4*k4+0], a0); a0 = fmaf(v0.y, w[4*k4+1], a0);
        a0 = fmaf(v0.z, w[4*k4+2], a0); a0 = fmaf(v0.w, w[4*k4+3], a0);
        a1 = fmaf(v1.x, w[4*k4+0], a1); a1 = fmaf(v1.y, w[4*k4+1], a1);
        a1 = fmaf(v1.z, w[4*k4+2], a1); a1 = fmaf(v1.w, w[4*k4+3], a1);
        a2 = fmaf(v2.x, w[4*k4+0], a2); a2 = fmaf(v2.y, w[4*k4+1], a2);
        a2 = fmaf(v2.z, w[4*k4+2], a2); a2 = fmaf(v2.w, w[4*k4+3], a2);
        a3 = fmaf(v3.x, w[4*k4+0], a3); a3 = fmaf(v3.y, w[4*k4+1], a3);
        a3 = fmaf(v3.z, w[4*k4+2], a3); a3 = fmaf(v3.w, w[4*k4+3], a3);
      }
      C[(size_t)(r0 + r + 0)*128 + t] = a0;
      C[(size_t)(r0 + r + 1)*128 + t] = a1;
      C[(size_t)(r0 + r + 2)*128 + t] = a2;
      C[(size_t)(r0 + r + 3)*128 + t] = a3;
    }
  } else {
    // Wg fold: w = W1c column t in regs; eW/eb staged in LDS
    float w[64];
    #pragma unroll
    for (int k = 0; k < 64; k++) w[k] = ldf(W1, wl + (size_t)128*128 + (size_t)k*128 + t, f32);
    for (int i = t; i < 20*64; i += 128) sA[i] = ldf(eW, eWo + i, f32);
    if (t < 64) sA[1280 + t] = ldf(eb, ebo + t, f32);
    __syncthreads();
    for (int g = 0; g < 20; g++){
      float acc = 0.f;
      #pragma unroll
      for (int k4 = 0; k4 < 16; k4++){
        float4 e = *(const float4*)&sA[g*64 + 4*k4];
        acc = fmaf(e.x, w[4*k4+0], acc); acc = fmaf(e.y, w[4*k4+1], acc);
        acc = fmaf(e.z, w[4*k4+2], acc); acc = fmaf(e.w, w[4*k4+3], acc);
      }
      Wg[g*128 + t] = acc;
    }
    float acc = ldf(b1, b1o + t, f32);
    #pragma unroll
    for (int k4 = 0; k4 < 16; k4++){
      float4 e = *(const float4*)&sA[1280 + 4*k4];
      acc = fmaf(e.x, w[4*k4+0], acc); acc = fmaf(e.y, w[4*k4+1], acc);
      acc = fmaf(e.z, w[4*k4+2], acc); acc = fmaf(e.w, w[4*k4+3], acc);
    }
    b1p[t] = acc;
  }
}

// ---------- aggregation: Sbuf[node][tt] = (1/K) sum_e relu(Xd+Xs[src]+b1p+g@Wg)
//   256 thr = 2 halves of 128. blocks 0..31: 32 atoms (K=8); 32..895: 8 grid
//   nodes (K=32). Wg in 20 regs; gauss read via ds_read_b128 (stride-24 rows). ----------
__global__ void __launch_bounds__(256) k_aggr(const float* __restrict__ Xs,
    const float* __restrict__ Xd, const int* __restrict__ nbrA,
    const int* __restrict__ nbrG, const float* __restrict__ node_pos,
    const float* __restrict__ offc, const float* __restrict__ Wg,
    const float* __restrict__ b1p, float* __restrict__ Sbuf)
{
  __shared__ __attribute__((aligned(16))) float sG[256*24];  // 24.6 KB
  __shared__ int   sN[256];
  __shared__ float sOff[40];
  int t = threadIdx.x;            // 256
  int b = blockIdx.x;
  int KK, node0; const int* nbr;
  if (b < 32){ KK = 8;  node0 = b*32;              nbr = nbrA + b*256; }
  else       { KK = 32; node0 = NATOMS + (b-32)*8; nbr = nbrG + (size_t)(b-32)*256; }
  if (t < 40) sOff[t] = offc[t];
  sN[t] = nbr[t];
  __syncthreads();
  {
    // one edge per thread: distance + 20 gaussians
    int node = node0 + ((b < 32) ? (t >> 3) : (t >> 5));
    int src = sN[t];
    float dx = node_pos[src*3+0] - node_pos[node*3+0];
    float dy = node_pos[src*3+1] - node_pos[node*3+1];
    float dz = node_pos[src*3+2] - node_pos[node*3+2];
    float dist = fminf(sqrtf(dx*dx + dy*dy + dz*dz), 5.0f);
    #pragma unroll
    for (int k = 0; k < 20; k++){
      float dd = dist - sOff[k];
      sG[t*24 + k] = expf(sOff[20+k] * dd * dd);
    }
  }
  int g = t >> 7, tt = t & 127;
  float w[20];
  #pragma unroll
  for (int k = 0; k < 20; k++) w[k] = Wg[k*128 + tt];   // column-constant -> regs
  float b1v = b1p[tt];
  __syncthreads();
  float rK = 1.f / KK;
  int nLoc = (b < 32) ? 16 : 4;
  int nbase = g * nLoc;
  for (int n = 0; n < nLoc; n++){
    int node = node0 + nbase + n;
    float zb = Xd[(size_t)node*128 + tt] + b1v;
    float S = 0.f;
    int ebase = (nbase + n) * KK;
    for (int e = 0; e < KK; e += 4){
      int i0 = ebase + e;
      int s0 = sN[i0], s1 = sN[i0+1], s2 = sN[i0+2], s3 = sN[i0+3];
      float a0 = zb + Xs[(size_t)s0*128 + tt];
      float a1 = zb + Xs[(size_t)s1*128 + tt];
      float a2 = zb + Xs[(size_t)s2*128 + tt];
      float a3 = zb + Xs[(size_t)s3*128 + tt];
      const float* g0 = &sG[i0*24];
      #pragma unroll
      for (int kq = 0; kq < 5; kq++){
        float4 ga = *(const float4*)(g0 + 4*kq);
        float4 gb = *(const float4*)(g0 + 24 + 4*kq);
        float4 gc = *(const float4*)(g0 + 48 + 4*kq);
        float4 gd = *(const float4*)(g0 + 72 + 4*kq);
        a0 = fmaf(ga.x, w[4*kq+0], a0); a0 = fmaf(ga.y, w[4*kq+1], a0);
        a0 = fmaf(ga.z, w[4*kq+2], a0); a0 = fmaf(ga.w, w[4*kq+3], a0);
        a1 = fmaf(gb.x, w[4*kq+0], a1); a1 = fmaf(gb.y, w[4*kq+1], a1);
        a1 = fmaf(gb.z, w[4*kq+2], a1); a1 = fmaf(gb.w, w[4*kq+3], a1);
        a2 = fmaf(gc.x, w[4*kq+0], a2); a2 = fmaf(gc.y, w[4*kq+1], a2);
        a2 = fmaf(gc.z, w[4*kq+2], a2); a2 = fmaf(gc.w, w[4*kq+3], a2);
        a3 = fmaf(gd.x, w[4*kq+0], a3); a3 = fmaf(gd.y, w[4*kq+1], a3);
        a3 = fmaf(gd.z, w[4*kq+2], a3); a3 = fmaf(gd.w, w[4*kq+3], a3);
      }
      S += fmaxf(a0,0.f) + fmaxf(a1,0.f) + fmaxf(a2,0.f) + fmaxf(a3,0.f);
    }
    Sbuf[(size_t)node*128 + tt] = S * rK;
  }
}

// ---------- output: x = hin + Sbuf@W2 + b2 -> LayerNorm; 32 rows/block, 256 thr ----------
// No local arrays / dynamic indexing; sS read via b128 broadcasts.
__global__ void __launch_bounds__(256) k_out(const float* __restrict__ hin,
    const float* __restrict__ Sbuf,
    const void* __restrict__ W2, const void* __restrict__ b2,
    const void* __restrict__ lng, const void* __restrict__ lnb,
    size_t w2o, size_t b2o, size_t lno,
    const int* __restrict__ flag,
    float* __restrict__ hout, float* __restrict__ out, int writeOut)
{
  __shared__ float sW2[128*64];   // 32 KB
  __shared__ __attribute__((aligned(16))) float sS[32*128];    // 16 KB
  int f32 = flag[0];
  int t = threadIdx.x;
  int r0 = blockIdx.x * 32;
  for (int i = t; i < 128*64; i += 256) sW2[i] = ldf(W2, w2o + i, f32);
  for (int i = t; i < 32*128; i += 256) sS[i] = Sbuf[(size_t)r0*128 + i];
  int w = t >> 6, c = t & 63;
  float b2v = ldf(b2, b2o + c, f32);
  float gv  = ldf(lng, lno + c, f32);
  float bv  = ldf(lnb, lno + c, f32);
  __syncthreads();
  for (int rr = w*8; rr < w*8 + 8; rr += 2){
    float a0 = 0.f, a1 = 0.f;
    const float* s0 = &sS[rr*128];
    const float* s1 = &sS[(rr+1)*128];
    #pragma unroll
    for (int kq = 0; kq < 32; kq++){
      float4 sv0 = *(const float4*)(s0 + 4*kq);
      float4 sv1 = *(const float4*)(s1 + 4*kq);
      a0 = fmaf(sv0.x, sW2[(4*kq+0)*64+c], a0);
      a0 = fmaf(sv0.y, sW2[(4*kq+1)*64+c], a0);
      a0 = fmaf(sv0.z, sW2[(4*kq+2)*64+c], a0);
      a0 = fmaf(sv0.w, sW2[(4*kq+3)*64+c], a0);
      a1 = fmaf(sv1.x, sW2[(4*kq+0)*64+c], a1);
      a1 = fmaf(sv1.y, sW2[(4*kq+1)*64+c], a1);
      a1 = fmaf(sv1.z, sW2[(4*kq+2)*64+c], a1);
      a1 = fmaf(sv1.w, sW2[(4*kq+3)*64+c], a1);
    }
    {
      int node = r0 + rr;
      float x = hin[(size_t)node*64 + c] + a0 + b2v;
      float s = x;
      #pragma unroll
      for (int m = 1; m < 64; m <<= 1) s += __shfl_xor(s, m);
      float mu = s * (1.f/64.f);
      float d = x - mu;
      float v = d * d;
      #pragma unroll
      for (int m = 1; m < 64; m <<= 1) v += __shfl_xor(v, m);
      v *= (1.f/64.f);
      float o = d / sqrtf(v + 1e-5f) * gv + bv;
      hout[(size_t)node*64 + c] = o;
      if (writeOut && node >= NATOMS) out[(size_t)(node - NATOMS)*64 + c] = o;
    }
    {
      int node = r0 + rr + 1;
      float x = hin[(size_t)node*64 + c] + a1 + b2v;
      float s = x;
      #pragma unroll
      for (int m = 1; m < 64; m <<= 1) s += __shfl_xor(s, m);
      float mu = s * (1.f/64.f);
      float d = x - mu;
      float v = d * d;
      #pragma unroll
      for (int m = 1; m < 64; m <<= 1) v += __shfl_xor(v, m);
      v *= (1.f/64.f);
      float o = d / sqrtf(v + 1e-5f) * gv + bv;
      hout[(size_t)node*64 + c] = o;
      if (writeOut && node >= NATOMS) out[(size_t)(node - NATOMS)*64 + c] = o;
    }
  }
}

extern "C" void kernel_launch(void* const* d_in, const int* in_sizes, int n_in,
                              void* d_out, int out_size, void* d_ws, size_t ws_size,
                              hipStream_t stream) {
  const void* pos    = d_in[0];
  const void* types  = d_in[1];
  // d_in[2] = batch (unused by the math)
  const void* edge_W = d_in[3];
  const void* edge_b = d_in[4];
  const void* W1     = d_in[5];
  const void* b1     = d_in[6];
  const void* W2     = d_in[7];
  const void* b2     = d_in[8];
  const void* lng    = d_in[9];
  const void* lnb    = d_in[10];

  const size_t NEED = (size_t)16 * 1024 * 1024;
  char* w = (ws_size >= NEED) ? (char*)d_ws : (char*)g_buf;
  if (w == nullptr) w = (char*)d_ws;   // last resort

  size_t o = 0;
  auto alloc = [&](size_t bytes)->char*{
    char* r = w + o; o = (o + bytes + 255) & ~(size_t)255; return r;
  };
  float*  node_pos = (float*) alloc((size_t)NNODES*3*4);
  float*  hA       = (float*) alloc((size_t)NNODES*CODE*4);
  float*  hB       = (float*) alloc((size_t)NNODES*CODE*4);
  float*  Xs       = (float*) alloc((size_t)NATOMS*HID*4);
  float*  Xd       = (float*) alloc((size_t)NNODES*HID*4);
  float*  Sbuf     = (float*) alloc((size_t)NNODES*HID*4);
  int*    nbrA     = (int*)   alloc((size_t)NATOMS*KA*4);
  int*    nbrG     = (int*)   alloc((size_t)NGRID*KG*4);
  float*  offc     = (float*) alloc(64*4);
  float*  Wg       = (float*) alloc(20*HID*4);
  float*  b1p      = (float*) alloc(HID*4);
  int*    flag     = (int*)   alloc(64*4);

  k0<<<2, 256, 0, stream>>>((const unsigned short*)pos,
                            (const unsigned short*)types, flag, offc);
  k_pre<<<3968, 256, 0, stream>>>(pos, types, flag, node_pos, hA, nbrA, nbrG);

  float* hin = hA; float* hout = hB;
  for (int l = 0; l < 4; l++){
    size_t wl  = (size_t)l*192*128;
    size_t eWo = (size_t)l*20*64, ebo = (size_t)l*64;
    size_t b1o = (size_t)l*128,   w2o = (size_t)l*128*64;
    size_t b2o = (size_t)l*64,    lno = (size_t)l*64;
    k_fold<<<1121, 128, 0, stream>>>(hin, W1, b1, edge_W, edge_b,
                                     wl, b1o, eWo, ebo, flag, Xd, Xs, Wg, b1p);
    k_aggr<<<32 + NGRID/8, 256, 0, stream>>>(Xs, Xd, nbrA, nbrG, node_pos,
                                             offc, Wg, b1p, Sbuf);
    k_out<<<NNODES/32, 256, 0, stream>>>(hin, Sbuf, W2, b2, lng, lnb,
                                         w2o, b2o, lno, flag,
                                         hout, (float*)d_out, (l == 3) ? 1 : 0);
    float* tmp = hin; hin = hout; hout = tmp;
  }
}